// Round 1
// baseline (854.514 us; speedup 1.0000x reference)
//
#include <hip/hip_runtime.h>
#include <hip/hip_bf16.h>
#include <cstdint>

#define Bc 2
#define Nc 3072
#define Hc 4
#define NQT (Nc/64)      // 48 query tiles
#define NW32 (Nc/32)     // 96 mask words per row
#define NTILES (Nc/32)   // 96 key tiles of 32

// ---------------- transpose W: [h][d][o] (x3 projections) -> Wt[p][h][o][d] ----------------
__global__ void wt_kernel(const float* __restrict__ Wq, const float* __restrict__ Wk,
                          const float* __restrict__ Wv, float* __restrict__ Wt)
{
    int i = blockIdx.x*256 + threadIdx.x;   // exactly 3*4*64*64 = 49152 threads
    int d = i & 63;
    int o = (i >> 6) & 63;
    int h = (i >> 12) & 3;
    int p = i >> 14;
    const float* W = (p == 0) ? Wq : (p == 1) ? Wk : Wv;
    Wt[i] = W[(h*64 + d)*64 + o];
}

// ---------------- QKV projection: lane = o, x-row wave-uniform (scalar loads) ----------------
__global__ __launch_bounds__(256) void qkv_kernel(
    const float* __restrict__ x, const float* __restrict__ Wt,
    const float* __restrict__ bq, const float* __restrict__ bk, const float* __restrict__ bv,
    float* __restrict__ QKV)
{
    const int lane = threadIdx.x & 63;
    int gw = blockIdx.x*4 + (threadIdx.x >> 6);   // 4608 waves
    int rc = gw % 192; gw /= 192;                 // row chunk (16 rows each)
    int p  = gw % 3;   gw /= 3;                   // 0=Q,1=K,2=V
    int h  = gw % Hc;
    int b  = gw / Hc;

    // per-lane weight column: Wt[p][h][o=lane][d]
    const float4* wr = (const float4*)(Wt + (((p*Hc + h)*64 + lane) << 6));
    float w[64];
    #pragma unroll
    for (int j = 0; j < 16; ++j) {
        float4 t = wr[j];
        w[4*j] = t.x; w[4*j+1] = t.y; w[4*j+2] = t.z; w[4*j+3] = t.w;
    }
    const float* bias = (p == 0) ? bq : (p == 1) ? bk : bv;
    float bb = bias[h*64 + lane];
    float* dst = QKV + (size_t)p*((size_t)Bc*Hc*Nc*64) + (((size_t)(b*Hc + h)*Nc) << 6);

    #pragma unroll 1
    for (int r = 0; r < 16; ++r) {
        int row = rc*16 + r;
        const float4* xr = (const float4*)(x + (((size_t)b*Nc + row) << 6));  // wave-uniform
        float s0 = 0.f, s1 = 0.f, s2 = 0.f, s3 = 0.f;
        #pragma unroll
        for (int j = 0; j < 16; ++j) {
            float4 xx = xr[j];
            s0 += xx.x*w[4*j];   s1 += xx.y*w[4*j+1];
            s2 += xx.z*w[4*j+2]; s3 += xx.w*w[4*j+3];
        }
        dst[((size_t)row << 6) + lane] = (s0+s1)+(s2+s3) + bb;   // coalesced (lane=o)
    }
}

// ---------------- bitpack adjacency: edge[b][n][m] int32 -> bit m of pmask ----------------
__global__ void pack_kernel(const int* __restrict__ edge, uint64_t* __restrict__ pmask64)
{
    int gw = blockIdx.x*4 + (threadIdx.x >> 6);
    int lane = threadIdx.x & 63;
    int chunk = gw % 48; gw /= 48;      // 64-key chunk
    int n = gw % Nc;
    int b = gw / Nc;
    int e = edge[((size_t)(b*Nc + n))*Nc + chunk*64 + lane];
    unsigned long long bal = __ballot(e != 0);
    if (lane == 0) pmask64[(size_t)(b*Nc + n)*48 + chunk] = bal;
}

// ---------------- flash partial: lane = query, keys split KS ways, no max (bounded scores) ----
__global__ __launch_bounds__(64, 3) void attn_partial(
    const float* __restrict__ QKV, const uint32_t* __restrict__ pmask,
    float* __restrict__ PA, float* __restrict__ PL,
    int ksplits, int tps)
{
    const int lane = threadIdx.x;
    int bid = blockIdx.x;
    int qt = bid % NQT;     bid /= NQT;
    int ks = bid % ksplits; bid /= ksplits;
    int h  = bid % Hc;
    int b  = bid / Hc;
    const int bh = b*Hc + h;
    const size_t SZ = (size_t)Bc*Hc*Nc*64;
    const float* Q = QKV;
    const float* K = QKV + SZ;
    const float* V = QKV + 2*SZ;

    int row = qt*64 + lane;
    const float4* qr = (const float4*)(Q + (((size_t)bh*Nc + row) << 6));
    float q[64];
    #pragma unroll
    for (int j = 0; j < 16; ++j) {
        float4 t = qr[j];
        q[4*j] = t.x; q[4*j+1] = t.y; q[4*j+2] = t.z; q[4*j+3] = t.w;
    }
    float acc[64];
    #pragma unroll
    for (int o = 0; o < 64; ++o) acc[o] = 0.f;
    float l = 0.f;

    const uint32_t* pmrow = pmask + (size_t)(b*Nc + row)*NW32;     // per-lane
    const float4*  kbase = (const float4*)(K + ((size_t)bh*Nc << 6));
    const float4*  vbase = (const float4*)(V + ((size_t)bh*Nc << 6));

    int t0 = ks*tps;
    #pragma unroll 1
    for (int t = t0; t < t0 + tps; ++t) {
        uint32_t mw = pmrow[t];
        const float4* kr = kbase + (size_t)t*32*16;   // wave-uniform base
        const float4* vr = vbase + (size_t)t*32*16;
        #pragma unroll 2
        for (int j = 0; j < 32; ++j) {
            float s0 = 0.f, s1 = 0.f, s2 = 0.f, s3 = 0.f;
            #pragma unroll
            for (int d2 = 0; d2 < 16; ++d2) {
                float4 kk = kr[j*16 + d2];            // broadcast (uniform) load
                s0 += q[4*d2]*kk.x;   s1 += q[4*d2+1]*kk.y;
                s2 += q[4*d2+2]*kk.z; s3 += q[4*d2+3]*kk.w;
            }
            float s = ((s0+s1)+(s2+s3)) * 0.125f;     // / sqrt(64)
            s = fmaxf(s, 0.f) + 0.2f*fminf(s, 0.f);   // leaky_relu 0.2
            float p = ((mw >> j) & 1u) ? __expf(s) : 0.f;   // masked -> exactly 0
            l += p;
            #pragma unroll
            for (int d2 = 0; d2 < 16; ++d2) {
                float4 vv = vr[j*16 + d2];            // broadcast (uniform) load
                acc[4*d2]   += p*vv.x; acc[4*d2+1] += p*vv.y;
                acc[4*d2+2] += p*vv.z; acc[4*d2+3] += p*vv.w;
            }
        }
    }

    // coalesced partial store, layout PA[b][h][ks][o][n]
    float* pa = PA + ((size_t)(bh*ksplits + ks)*64)*Nc + qt*64 + lane;
    #pragma unroll
    for (int o = 0; o < 64; ++o) pa[(size_t)o*Nc] = acc[o];
    PL[(size_t)(bh*ksplits + ks)*Nc + row] = l;
}

// ---------------- merge: sum key-splits, divide, mean heads, leaky ----------------
__global__ void merge_kernel(const float* __restrict__ PA, const float* __restrict__ PL,
                             float* __restrict__ out, int ksplits)
{
    int gid = blockIdx.x*256 + threadIdx.x;   // B*64*N threads, n innermost
    int n = gid % Nc;
    int o = (gid / Nc) & 63;
    int b = gid / (Nc*64);
    float ft = 0.f;
    for (int h = 0; h < Hc; ++h) {
        float A = 0.f, L = 0.f;
        for (int ks = 0; ks < ksplits; ++ks) {
            A += PA[(((size_t)((b*Hc+h)*ksplits + ks)*64) + o)*Nc + n];
            L += PL[((size_t)((b*Hc+h)*ksplits + ks))*Nc + n];
        }
        ft += A / L;
    }
    ft *= 0.25f;   // mean over H=4 heads
    out[((size_t)(b*Nc + n) << 6) + o] = fmaxf(ft, 0.f) + 0.2f*fminf(ft, 0.f);
}

extern "C" void kernel_launch(void* const* d_in, const int* in_sizes, int n_in,
                              void* d_out, int out_size, void* d_ws, size_t ws_size,
                              hipStream_t stream)
{
    const float* x    = (const float*)d_in[0];
    const int*   edge = (const int*)d_in[1];
    const float* Wv   = (const float*)d_in[2];
    const float* bv   = (const float*)d_in[3];
    const float* Wq   = (const float*)d_in[4];
    const float* bq   = (const float*)d_in[5];
    const float* Wk   = (const float*)d_in[6];
    const float* bk   = (const float*)d_in[7];
    float* out = (float*)d_out;

    const size_t SZ = (size_t)Bc*Hc*Nc*64;     // per-projection elems
    float* ws  = (float*)d_ws;
    float* Wt  = ws;
    float* QKV = Wt + 3*Hc*64*64;

    // pick the largest key-split count that fits in workspace
    int KSv = 8;
    for (;;) {
        size_t need_f = (size_t)(3*Hc*64*64) + 3*SZ
                      + (size_t)Bc*Hc*KSv*64*Nc + (size_t)Bc*Hc*KSv*Nc;
        size_t need = need_f*4 + (size_t)Bc*Nc*NW32*4;
        if (need <= ws_size || KSv == 1) break;
        KSv >>= 1;
    }
    float* PA = QKV + 3*SZ;
    float* PL = PA + (size_t)Bc*Hc*KSv*64*Nc;
    uint32_t* pmask = (uint32_t*)(PL + (size_t)Bc*Hc*KSv*Nc);

    hipLaunchKernelGGL(wt_kernel,    dim3(192),  dim3(256), 0, stream, Wq, Wk, Wv, Wt);
    hipLaunchKernelGGL(qkv_kernel,   dim3(1152), dim3(256), 0, stream, x, Wt, bq, bk, bv, QKV);
    hipLaunchKernelGGL(pack_kernel,  dim3((Bc*Nc*48)/4), dim3(256), 0, stream,
                       edge, (uint64_t*)pmask);
    hipLaunchKernelGGL(attn_partial, dim3(Bc*Hc*KSv*NQT), dim3(64), 0, stream,
                       QKV, pmask, PA, PL, KSv, NTILES/KSv);
    hipLaunchKernelGGL(merge_kernel, dim3((Bc*64*Nc)/256), dim3(256), 0, stream,
                       PA, PL, out, KSv);
}

// Round 2
// 373.736 us; speedup vs baseline: 2.2864x; 2.2864x over previous
//
#include <hip/hip_runtime.h>
#include <hip/hip_bf16.h>
#include <cstdint>

#define Bc 2
#define Nc 3072
#define Hc 4
#define NW32 (Nc/32)     // 96 mask words per row

typedef __bf16 bf16x8 __attribute__((ext_vector_type(8)));
typedef float  f32x4  __attribute__((ext_vector_type(4)));

static __device__ __forceinline__ f32x4 mfma16(bf16x8 a, bf16x8 b, f32x4 c) {
    return __builtin_amdgcn_mfma_f32_16x16x32_bf16(a, b, c, 0, 0, 0);
}

// ---------------- transpose W: [h][d][o] (x3 projections) -> Wt[p][h][o][d] ----------------
__global__ void wt_kernel(const float* __restrict__ Wq, const float* __restrict__ Wk,
                          const float* __restrict__ Wv, float* __restrict__ Wt)
{
    int i = blockIdx.x*256 + threadIdx.x;   // exactly 3*4*64*64 = 49152 threads
    int d = i & 63;
    int o = (i >> 6) & 63;
    int h = (i >> 12) & 3;
    int p = i >> 14;
    const float* W = (p == 0) ? Wq : (p == 1) ? Wk : Wv;
    Wt[i] = W[(h*64 + d)*64 + o];
}

// ---------------- QKV projection -> split bf16 hi/lo. Q,K: [bh][n][64]; V: [bh][o][n] ------
__global__ __launch_bounds__(256) void qkv_kernel(
    const float* __restrict__ x, const float* __restrict__ Wt,
    const float* __restrict__ bq, const float* __restrict__ bk, const float* __restrict__ bv,
    __bf16* __restrict__ Qh, __bf16* __restrict__ Ql,
    __bf16* __restrict__ Kh, __bf16* __restrict__ Kl,
    __bf16* __restrict__ Vth, __bf16* __restrict__ Vtl)
{
    const int lane = threadIdx.x & 63;
    int gw = blockIdx.x*4 + (threadIdx.x >> 6);   // 4608 waves
    int rc = gw % 192; gw /= 192;                 // row chunk (16 rows each)
    int p  = gw % 3;   gw /= 3;                   // 0=Q,1=K,2=V
    int h  = gw % Hc;
    int b  = gw / Hc;
    const int bh = b*Hc + h;

    // per-lane weight column: Wt[p][h][o=lane][d]
    const float4* wr = (const float4*)(Wt + (((p*Hc + h)*64 + lane) << 6));
    float w[64];
    #pragma unroll
    for (int j = 0; j < 16; ++j) {
        float4 t = wr[j];
        w[4*j] = t.x; w[4*j+1] = t.y; w[4*j+2] = t.z; w[4*j+3] = t.w;
    }
    const float* bias = (p == 0) ? bq : (p == 1) ? bk : bv;
    float bb = bias[h*64 + lane];

    #pragma unroll 1
    for (int r = 0; r < 16; ++r) {
        int row = rc*16 + r;
        const float4* xr = (const float4*)(x + (((size_t)b*Nc + row) << 6));  // wave-uniform
        float s0 = 0.f, s1 = 0.f, s2 = 0.f, s3 = 0.f;
        #pragma unroll
        for (int j = 0; j < 16; ++j) {
            float4 xx = xr[j];
            s0 += xx.x*w[4*j];   s1 += xx.y*w[4*j+1];
            s2 += xx.z*w[4*j+2]; s3 += xx.w*w[4*j+3];
        }
        float val = (s0+s1)+(s2+s3) + bb;
        __bf16 hi = (__bf16)val;
        __bf16 lo = (__bf16)(val - (float)hi);
        if (p == 0) {
            size_t i0 = (((size_t)bh*Nc + row) << 6) + lane;   // [bh][n][d], coalesced
            Qh[i0] = hi; Ql[i0] = lo;
        } else if (p == 1) {
            size_t i0 = (((size_t)bh*Nc + row) << 6) + lane;
            Kh[i0] = hi; Kl[i0] = lo;
        } else {
            size_t i2 = ((size_t)bh*64 + lane)*Nc + row;       // [bh][o][n] transposed
            Vth[i2] = hi; Vtl[i2] = lo;
        }
    }
}

// ---------------- bitpack adjacency: edge[b][n][m] int32 -> bit m ----------------
__global__ void pack_kernel(const int* __restrict__ edge, uint64_t* __restrict__ pmask64)
{
    int gw = blockIdx.x*4 + (threadIdx.x >> 6);
    int lane = threadIdx.x & 63;
    int chunk = gw % 48; gw /= 48;      // 64-key chunk
    int n = gw % Nc;
    int b = gw / Nc;
    int e = edge[((size_t)(b*Nc + n))*Nc + chunk*64 + lane];
    unsigned long long bal = __ballot(e != 0);
    if (lane == 0) pmask64[(size_t)(b*Nc + n)*48 + chunk] = bal;
}

// ---------------- MFMA flash attention partial (split-bf16 emulated f32) ----------------
// wave = 16 q-rows; loop 32-key tiles; S = qh*kh + qh*kl + ql*kh; p = bf16(exp(leaky(S/8)))
// masked -> 0; l = sum of quantized p; PV = p*(vh+vl). No max-tracking (scores bounded).
__global__ __launch_bounds__(256, 4) void attn_mfma(
    const __bf16* __restrict__ Qh, const __bf16* __restrict__ Ql,
    const __bf16* __restrict__ Kh, const __bf16* __restrict__ Kl,
    const __bf16* __restrict__ Vth, const __bf16* __restrict__ Vtl,
    const uint32_t* __restrict__ pmask,
    float* __restrict__ PA, float* __restrict__ PL, int KS, int tps)
{
    __shared__ __bf16 lds_p[4][16][32];   // per-wave private P tile
    const int lane = threadIdx.x & 63;
    const int w    = threadIdx.x >> 6;
    int gw = blockIdx.x*4 + w;
    int rt = gw % 192; gw /= 192;         // row tile (16 rows)
    int ks = gw % KS;  gw /= KS;          // key split
    int bh = gw;                          // 0..7
    int b  = bh >> 2;

    const int l15 = lane & 15, l4 = lane >> 4;
    const int q4  = l4*4;
    const int rowbase = rt*16;

    // hoisted Q A-fragments (rows rowbase..+15, d=64 in two k-steps), hi+lo
    size_t qoff = (((size_t)bh*Nc + rowbase + l15) << 6) + l4*8;
    bf16x8 qh0 = *(const bf16x8*)(Qh + qoff);
    bf16x8 qh1 = *(const bf16x8*)(Qh + qoff + 32);
    bf16x8 ql0 = *(const bf16x8*)(Ql + qoff);
    bf16x8 ql1 = *(const bf16x8*)(Ql + qoff + 32);

    f32x4 acc[4];
    #pragma unroll
    for (int ot = 0; ot < 4; ++ot) acc[ot] = (f32x4){0.f, 0.f, 0.f, 0.f};
    float lsum[4] = {0.f, 0.f, 0.f, 0.f};

    const uint32_t* pm = pmask + ((size_t)b*Nc + rowbase)*NW32;

    const int t0 = ks*tps;
    #pragma unroll 1
    for (int t = t0; t < t0 + tps; ++t) {
        const int kt0 = t*32;
        // ---- QK^T: two 16-col C-frags over keys kt0..kt0+31 ----
        size_t koff0 = (((size_t)bh*Nc + kt0 + l15) << 6) + l4*8;   // cfrag 0: keys kt0+l15
        size_t koff1 = koff0 + (16 << 6);                            // cfrag 1: +16 keys
        f32x4 s0 = (f32x4){0.f,0.f,0.f,0.f};
        f32x4 s1 = (f32x4){0.f,0.f,0.f,0.f};
        {
            bf16x8 ka = *(const bf16x8*)(Kh + koff0);
            bf16x8 kb = *(const bf16x8*)(Kh + koff0 + 32);
            bf16x8 la = *(const bf16x8*)(Kl + koff0);
            bf16x8 lb = *(const bf16x8*)(Kl + koff0 + 32);
            s0 = mfma16(qh0, ka, s0); s0 = mfma16(qh1, kb, s0);
            s0 = mfma16(qh0, la, s0); s0 = mfma16(qh1, lb, s0);
            s0 = mfma16(ql0, ka, s0); s0 = mfma16(ql1, kb, s0);
        }
        {
            bf16x8 ka = *(const bf16x8*)(Kh + koff1);
            bf16x8 kb = *(const bf16x8*)(Kh + koff1 + 32);
            bf16x8 la = *(const bf16x8*)(Kl + koff1);
            bf16x8 lb = *(const bf16x8*)(Kl + koff1 + 32);
            s1 = mfma16(qh0, ka, s1); s1 = mfma16(qh1, kb, s1);
            s1 = mfma16(qh0, la, s1); s1 = mfma16(qh1, lb, s1);
            s1 = mfma16(ql0, ka, s1); s1 = mfma16(ql1, kb, s1);
        }
        // ---- leaky + mask + exp + quantize; write P tile to wave-private LDS ----
        #pragma unroll
        for (int r = 0; r < 4; ++r) {
            uint32_t mw = pm[(size_t)(q4 + r)*NW32 + t];   // 16 lanes/quarter share addr
            float a0 = s0[r]*0.125f, a1 = s1[r]*0.125f;
            a0 = fmaxf(a0, 0.f) + 0.2f*fminf(a0, 0.f);
            a1 = fmaxf(a1, 0.f) + 0.2f*fminf(a1, 0.f);
            float p0 = ((mw >> l15) & 1u)        ? __expf(a0) : 0.f;
            float p1 = ((mw >> (16 + l15)) & 1u) ? __expf(a1) : 0.f;
            __bf16 pb0 = (__bf16)p0;
            __bf16 pb1 = (__bf16)p1;
            lsum[r] += (float)pb0 + (float)pb1;    // denominator from SAME quantized values
            lds_p[w][q4 + r][l15]      = pb0;
            lds_p[w][q4 + r][16 + l15] = pb1;
        }
        // ---- PV: A-frag from LDS, B-frags from Vt[o][n] (hi+lo) ----
        bf16x8 pa = *(const bf16x8*)&lds_p[w][l15][l4*8];
        #pragma unroll
        for (int ot = 0; ot < 4; ++ot) {
            size_t voff = ((size_t)bh*64 + ot*16 + l15)*Nc + kt0 + l4*8;
            bf16x8 vh = *(const bf16x8*)(Vth + voff);
            bf16x8 vl = *(const bf16x8*)(Vtl + voff);
            acc[ot] = mfma16(pa, vh, acc[ot]);
            acc[ot] = mfma16(pa, vl, acc[ot]);
        }
    }

    // ---- store partials: PA[bh][ks][n(16 rows)][o64], PL[bh][ks][n] ----
    float* pa_out = PA + (((size_t)(bh*KS + ks)*Nc + rowbase) << 6);
    #pragma unroll
    for (int ot = 0; ot < 4; ++ot)
        #pragma unroll
        for (int reg = 0; reg < 4; ++reg)
            pa_out[(size_t)((q4 + reg) << 6) + ot*16 + l15] = acc[ot][reg];

    #pragma unroll
    for (int r = 0; r < 4; ++r) {
        float v = lsum[r];
        v += __shfl_xor(v, 1); v += __shfl_xor(v, 2);
        v += __shfl_xor(v, 4); v += __shfl_xor(v, 8);
        if (l15 == 0) PL[(size_t)(bh*KS + ks)*Nc + rowbase + q4 + r] = v;
    }
}

// ---------------- merge: sum key-splits, divide, mean heads, leaky ----------------
__global__ void merge_kernel(const float* __restrict__ PA, const float* __restrict__ PL,
                             float* __restrict__ out, int KS)
{
    int gid = blockIdx.x*256 + threadIdx.x;   // B*N*64 threads, o innermost
    int o  = gid & 63;
    int bn = gid >> 6;
    int n  = bn % Nc;
    int b  = bn / Nc;
    float ft = 0.f;
    for (int h = 0; h < Hc; ++h) {
        int bh = b*Hc + h;
        float A = 0.f, L = 0.f;
        for (int ks = 0; ks < KS; ++ks) {
            A += PA[(((size_t)(bh*KS + ks)*Nc + n) << 6) + o];
            L += PL[(size_t)(bh*KS + ks)*Nc + n];
        }
        ft += A / L;
    }
    ft *= 0.25f;   // mean over H=4 heads
    out[((size_t)bn << 6) + o] = fmaxf(ft, 0.f) + 0.2f*fminf(ft, 0.f);
}

extern "C" void kernel_launch(void* const* d_in, const int* in_sizes, int n_in,
                              void* d_out, int out_size, void* d_ws, size_t ws_size,
                              hipStream_t stream)
{
    const float* x    = (const float*)d_in[0];
    const int*   edge = (const int*)d_in[1];
    const float* Wv   = (const float*)d_in[2];
    const float* bv   = (const float*)d_in[3];
    const float* Wq   = (const float*)d_in[4];
    const float* bq   = (const float*)d_in[5];
    const float* Wk   = (const float*)d_in[6];
    const float* bk   = (const float*)d_in[7];
    float* out = (float*)d_out;

    const size_t PROJ = (size_t)Bc*Hc*Nc*64;        // elems per projection
    char* p = (char*)d_ws;
    float* Wt = (float*)p;              p += 3*Hc*64*64*sizeof(float);
    __bf16* Qh  = (__bf16*)p;           p += PROJ*2;
    __bf16* Ql  = (__bf16*)p;           p += PROJ*2;
    __bf16* Kh  = (__bf16*)p;           p += PROJ*2;
    __bf16* Kl  = (__bf16*)p;           p += PROJ*2;
    __bf16* Vth = (__bf16*)p;           p += PROJ*2;
    __bf16* Vtl = (__bf16*)p;           p += PROJ*2;
    uint32_t* pmask = (uint32_t*)p;     p += (size_t)Bc*Nc*NW32*4;

    // pick largest key-split that fits remaining workspace
    int KS = 4;
    for (;;) {
        size_t need = (size_t)(p - (char*)d_ws)
                    + (size_t)Bc*Hc*KS*Nc*64*4     // PA
                    + (size_t)Bc*Hc*KS*Nc*4;       // PL
        if (need <= ws_size || KS == 1) break;
        KS >>= 1;
    }
    float* PA = (float*)p;              p += (size_t)Bc*Hc*KS*Nc*64*4;
    float* PL = (float*)p;

    hipLaunchKernelGGL(wt_kernel,   dim3(192),  dim3(256), 0, stream, Wq, Wk, Wv, Wt);
    hipLaunchKernelGGL(qkv_kernel,  dim3(1152), dim3(256), 0, stream,
                       x, Wt, bq, bk, bv, Qh, Ql, Kh, Kl, Vth, Vtl);
    hipLaunchKernelGGL(pack_kernel, dim3((Bc*Nc*48)/4), dim3(256), 0, stream,
                       edge, (uint64_t*)pmask);
    hipLaunchKernelGGL(attn_mfma,   dim3(Bc*Hc*KS*(Nc/16)/4), dim3(256), 0, stream,
                       Qh, Ql, Kh, Kl, Vth, Vtl, pmask, PA, PL, KS, (Nc/32)/KS);
    hipLaunchKernelGGL(merge_kernel, dim3((Bc*Nc*64)/256), dim3(256), 0, stream,
                       PA, PL, out, KS);
}

// Round 3
// 159.996 us; speedup vs baseline: 5.3408x; 2.3359x over previous
//
#include <hip/hip_runtime.h>
#include <hip/hip_bf16.h>
#include <cstdint>

#define Bc 2
#define Nc 3072
#define Hc 4
#define NW32 (Nc/32)     // 96 mask words (32-key tiles) per row

typedef __bf16 bf16x8 __attribute__((ext_vector_type(8)));
typedef float  f32x4  __attribute__((ext_vector_type(4)));

static __device__ __forceinline__ f32x4 mfma16(bf16x8 a, bf16x8 b, f32x4 c) {
    return __builtin_amdgcn_mfma_f32_16x16x32_bf16(a, b, c, 0, 0, 0);
}

static __device__ __forceinline__ void gload_lds16(const void* g, void* l) {
    __builtin_amdgcn_global_load_lds((const __attribute__((address_space(1))) void*)g,
                                     (__attribute__((address_space(3))) void*)l, 16, 0, 0);
}

// ---------------- transpose W: [h][d][o] (x3) -> Wt[p][h][o][d] ----------------
__global__ void wt_kernel(const float* __restrict__ Wq, const float* __restrict__ Wk,
                          const float* __restrict__ Wv, float* __restrict__ Wt)
{
    int i = blockIdx.x*256 + threadIdx.x;   // 3*4*64*64 = 49152 threads
    int d = i & 63;
    int o = (i >> 6) & 63;
    int h = (i >> 12) & 3;
    int p = i >> 14;
    const float* W = (p == 0) ? Wq : (p == 1) ? Wk : Wv;
    Wt[i] = W[(h*64 + d)*64 + o];
}

// ---------------- QKV projection -> split bf16 hi/lo, all [bh][n][64] coalesced ------
__global__ __launch_bounds__(256) void qkv_kernel(
    const float* __restrict__ x, const float* __restrict__ Wt,
    const float* __restrict__ bq, const float* __restrict__ bk, const float* __restrict__ bv,
    __bf16* __restrict__ Qh, __bf16* __restrict__ Ql,
    __bf16* __restrict__ Kh, __bf16* __restrict__ Kl,
    __bf16* __restrict__ Vh0, __bf16* __restrict__ Vl0)
{
    const int lane = threadIdx.x & 63;
    int gw = blockIdx.x*4 + (threadIdx.x >> 6);   // 4608 waves
    int rc = gw % 192; gw /= 192;                 // row chunk (16 rows)
    int p  = gw % 3;   gw /= 3;                   // 0=Q,1=K,2=V
    int h  = gw % Hc;
    int b  = gw / Hc;
    const int bh = b*Hc + h;

    const float4* wr = (const float4*)(Wt + (((p*Hc + h)*64 + lane) << 6));
    float w[64];
    #pragma unroll
    for (int j = 0; j < 16; ++j) {
        float4 t = wr[j];
        w[4*j] = t.x; w[4*j+1] = t.y; w[4*j+2] = t.z; w[4*j+3] = t.w;
    }
    const float* bias = (p == 0) ? bq : (p == 1) ? bk : bv;
    float bb = bias[h*64 + lane];
    __bf16* dh = (p == 0) ? Qh : (p == 1) ? Kh : Vh0;
    __bf16* dl = (p == 0) ? Ql : (p == 1) ? Kl : Vl0;

    #pragma unroll 1
    for (int r = 0; r < 16; ++r) {
        int row = rc*16 + r;
        const float4* xr = (const float4*)(x + (((size_t)b*Nc + row) << 6));
        float s0 = 0.f, s1 = 0.f, s2 = 0.f, s3 = 0.f;
        #pragma unroll
        for (int j = 0; j < 16; ++j) {
            float4 xx = xr[j];
            s0 += xx.x*w[4*j];   s1 += xx.y*w[4*j+1];
            s2 += xx.z*w[4*j+2]; s3 += xx.w*w[4*j+3];
        }
        float val = (s0+s1)+(s2+s3) + bb;
        __bf16 hi = (__bf16)val;
        __bf16 lo = (__bf16)(val - (float)hi);
        size_t i0 = (((size_t)bh*Nc + row) << 6) + lane;
        dh[i0] = hi; dl[i0] = lo;
    }
}

// ---------------- V transpose: [bh][n][o] -> Vt[bh][o][n] (hi/lo) ----------------
__global__ void vt_kernel(const __bf16* __restrict__ Vh0, const __bf16* __restrict__ Vl0,
                          __bf16* __restrict__ Vth, __bf16* __restrict__ Vtl)
{
    __shared__ __bf16 tile[2][64][72];   // +8 pad kills read conflicts
    int bh = blockIdx.x / 48;
    int n0 = (blockIdx.x % 48) * 64;
    int t = threadIdx.x;
    int r = t >> 2, seg = (t & 3) * 16;
    size_t ibase = (((size_t)bh*Nc + n0 + r) << 6) + seg;
    *(bf16x8*)&tile[0][r][seg]     = *(const bf16x8*)(Vh0 + ibase);
    *(bf16x8*)&tile[0][r][seg + 8] = *(const bf16x8*)(Vh0 + ibase + 8);
    *(bf16x8*)&tile[1][r][seg]     = *(const bf16x8*)(Vl0 + ibase);
    *(bf16x8*)&tile[1][r][seg + 8] = *(const bf16x8*)(Vl0 + ibase + 8);
    __syncthreads();
    __bf16 oh[16], ol[16];
    #pragma unroll
    for (int j = 0; j < 16; ++j) { oh[j] = tile[0][seg + j][r]; ol[j] = tile[1][seg + j][r]; }
    size_t obase = ((size_t)bh*64 + r)*Nc + n0 + seg;
    *(bf16x8*)(Vth + obase)     = *(bf16x8*)&oh[0];
    *(bf16x8*)(Vth + obase + 8) = *(bf16x8*)&oh[8];
    *(bf16x8*)(Vtl + obase)     = *(bf16x8*)&ol[0];
    *(bf16x8*)(Vtl + obase + 8) = *(bf16x8*)&ol[8];
}

// ---------------- pack adjacency transposed: pmT[b][w][n], bit j = edge[b][n][32w+j] ----
__global__ void pack_kernel(const int* __restrict__ edge, uint32_t* __restrict__ pmT)
{
    int gw = blockIdx.x*4 + (threadIdx.x >> 6);   // 9216 waves
    int lane = threadIdx.x & 63;
    int ng = gw % 48; gw /= 48;
    int w  = gw % NW32; gw /= NW32;
    int b  = gw;
    int n = ng*64 + lane;
    const uint4* ep = (const uint4*)(edge + ((size_t)b*Nc + n)*Nc + w*32);
    uint32_t word = 0;
    #pragma unroll
    for (int i = 0; i < 8; ++i) {
        uint4 e = ep[i];
        word |= (e.x ? 1u : 0u) << (4*i);
        word |= (e.y ? 1u : 0u) << (4*i + 1);
        word |= (e.z ? 1u : 0u) << (4*i + 2);
        word |= (e.w ? 1u : 0u) << (4*i + 3);
    }
    pmT[((size_t)b*NW32 + w)*Nc + n] = word;    // coalesced
}

// ---------------- flash attention: 4-wave block, 128 q rows, LDS-shared K/V ----------------
__global__ __launch_bounds__(256, 3) void attn_mfma(
    const __bf16* __restrict__ Qh, const __bf16* __restrict__ Ql,
    const __bf16* __restrict__ Kh, const __bf16* __restrict__ Kl,
    const __bf16* __restrict__ Vth, const __bf16* __restrict__ Vtl,
    const uint32_t* __restrict__ pmT,
    float* __restrict__ PA, float* __restrict__ PL, int KS, int tps)
{
    __shared__ __align__(16) __bf16 ldsK[2][2][32][64];  // [buf][hi/lo][key][d swizzled] 16KB
    __shared__ __align__(16) __bf16 ldsV[2][2][64][32];  // [buf][hi/lo][o][key]          16KB
    __shared__ __align__(16) __bf16 ldsP[4][2][16][32];  // [wave][qb][row][col swizzled]  8KB

    const int lane = threadIdx.x & 63;
    const int w    = threadIdx.x >> 6;
    const int l15 = lane & 15, l4 = lane >> 4;
    int gb = blockIdx.x;
    int qt = gb % 24; gb /= 24;
    int ks = gb % KS; gb /= KS;
    const int bh = gb, b = bh >> 2;
    const int qrow0 = qt*128 + w*32;      // wave's first q row (2 q-blocks of 16)

    // ---- Q fragments (hi/lo, 2 q-blocks, d=64 as two k-steps) ----
    bf16x8 qhA[2][2], qlA[2][2];
    #pragma unroll
    for (int qb = 0; qb < 2; ++qb) {
        size_t qoff = (((size_t)bh*Nc + qrow0 + qb*16 + l15) << 6) + l4*8;
        qhA[qb][0] = *(const bf16x8*)(Qh + qoff);
        qhA[qb][1] = *(const bf16x8*)(Qh + qoff + 32);
        qlA[qb][0] = *(const bf16x8*)(Ql + qoff);
        qlA[qb][1] = *(const bf16x8*)(Ql + qoff + 32);
    }

    // ---- staging setup: wave w stages one plane {Kh,Kl,Vth,Vtl} ----
    const __bf16* gplane;
    char* lbase[2];
    uint32_t goff[4];
    if (w < 2) {
        gplane = (w == 0) ? Kh : Kl;
        #pragma unroll
        for (int i = 0; i < 4; ++i) {
            int s = i*64 + lane, key = s >> 3, c = s & 7;
            goff[i] = (uint32_t)((bh*Nc + key)*128 + ((c ^ (key & 7)) << 4));
        }
        lbase[0] = (char*)&ldsK[0][w][0][0];
        lbase[1] = (char*)&ldsK[1][w][0][0];
    } else {
        gplane = (w == 2) ? Vth : Vtl;
        #pragma unroll
        for (int i = 0; i < 4; ++i) {
            int s = i*64 + lane, o = s >> 2, j = s & 3;
            goff[i] = (uint32_t)((bh*64 + o)*(Nc*2) + j*16);
        }
        lbase[0] = (char*)&ldsV[0][w - 2][0][0];
        lbase[1] = (char*)&ldsV[1][w - 2][0][0];
    }
    const uint32_t tstep = (w < 2) ? 4096u : 64u;

    f32x4 acc[2][4];
    #pragma unroll
    for (int qb = 0; qb < 2; ++qb)
        #pragma unroll
        for (int ot = 0; ot < 4; ++ot) acc[qb][ot] = (f32x4){0.f, 0.f, 0.f, 0.f};
    float lsum[2][4] = {{0.f,0.f,0.f,0.f},{0.f,0.f,0.f,0.f}};

    const int t0 = ks*tps;

    // prologue stage
    {
        const char* gp = (const char*)gplane + (size_t)t0*tstep;
        #pragma unroll
        for (int i = 0; i < 4; ++i) gload_lds16(gp + goff[i], lbase[0] + i*1024);
    }
    asm volatile("s_waitcnt vmcnt(0)" ::: "memory");
    __syncthreads();

    int cur = 0;
    #pragma unroll 1
    for (int it = 0; it < tps; ++it) {
        const int t = t0 + it;
        // stage next tile into other buffer (overlaps with compute below)
        if (it + 1 < tps) {
            const char* gp = (const char*)gplane + (size_t)(t + 1)*tstep;
            #pragma unroll
            for (int i = 0; i < 4; ++i) gload_lds16(gp + goff[i], lbase[cur ^ 1] + i*1024);
        }

        // ---- QK^T (split-bf16, 3 terms) ----
        f32x4 sc[2][2];
        #pragma unroll
        for (int qb = 0; qb < 2; ++qb)
            #pragma unroll
            for (int cf = 0; cf < 2; ++cf) sc[qb][cf] = (f32x4){0.f,0.f,0.f,0.f};
        #pragma unroll
        for (int cf = 0; cf < 2; ++cf) {
            const int key = cf*16 + l15;
            const int sw = (key & 7) << 3;
            const bf16x8 ka = *(const bf16x8*)&ldsK[cur][0][key][(l4 << 3) ^ sw];
            const bf16x8 kb = *(const bf16x8*)&ldsK[cur][0][key][((l4 + 4) << 3) ^ sw];
            const bf16x8 la = *(const bf16x8*)&ldsK[cur][1][key][(l4 << 3) ^ sw];
            const bf16x8 lb = *(const bf16x8*)&ldsK[cur][1][key][((l4 + 4) << 3) ^ sw];
            #pragma unroll
            for (int qb = 0; qb < 2; ++qb) {
                sc[qb][cf] = mfma16(qhA[qb][0], ka, sc[qb][cf]);
                sc[qb][cf] = mfma16(qhA[qb][1], kb, sc[qb][cf]);
                sc[qb][cf] = mfma16(qhA[qb][0], la, sc[qb][cf]);
                sc[qb][cf] = mfma16(qhA[qb][1], lb, sc[qb][cf]);
                sc[qb][cf] = mfma16(qlA[qb][0], ka, sc[qb][cf]);
                sc[qb][cf] = mfma16(qlA[qb][1], kb, sc[qb][cf]);
            }
        }

        // ---- softmax numerator + P tile (wave-private swizzled LDS) ----
        #pragma unroll
        for (int qb = 0; qb < 2; ++qb) {
            const uint4 mw4 = *(const uint4*)(pmT + ((size_t)b*NW32 + t)*Nc + qrow0 + qb*16 + 4*l4);
            const uint32_t mws[4] = {mw4.x, mw4.y, mw4.z, mw4.w};
            #pragma unroll
            for (int r = 0; r < 4; ++r) {
                float a0 = sc[qb][0][r]*0.125f, a1 = sc[qb][1][r]*0.125f;
                a0 = fmaxf(a0, 0.f) + 0.2f*fminf(a0, 0.f);
                a1 = fmaxf(a1, 0.f) + 0.2f*fminf(a1, 0.f);
                float p0 = ((mws[r] >> l15) & 1u)        ? __expf(a0) : 0.f;
                float p1 = ((mws[r] >> (16 + l15)) & 1u) ? __expf(a1) : 0.f;
                __bf16 pb0 = (__bf16)p0, pb1 = (__bf16)p1;
                lsum[qb][r] += (float)pb0 + (float)pb1;   // denom from SAME quantized values
                const int row = 4*l4 + r;
                ldsP[w][qb][row][(((l15 >> 3) ^ l4) << 3)       | (l15 & 7)] = pb0;
                ldsP[w][qb][row][((((l15 >> 3) + 2) ^ l4) << 3) | (l15 & 7)] = pb1;
            }
        }

        // ---- PV ----
        const bf16x8 pa0 = *(const bf16x8*)&ldsP[w][0][l15][(l4 ^ ((l15 >> 2) & 3)) << 3];
        const bf16x8 pa1 = *(const bf16x8*)&ldsP[w][1][l15][(l4 ^ ((l15 >> 2) & 3)) << 3];
        #pragma unroll
        for (int ot = 0; ot < 4; ++ot) {
            const bf16x8 vh = *(const bf16x8*)&ldsV[cur][0][ot*16 + l15][l4 << 3];
            const bf16x8 vl = *(const bf16x8*)&ldsV[cur][1][ot*16 + l15][l4 << 3];
            acc[0][ot] = mfma16(pa0, vh, acc[0][ot]);
            acc[0][ot] = mfma16(pa0, vl, acc[0][ot]);
            acc[1][ot] = mfma16(pa1, vh, acc[1][ot]);
            acc[1][ot] = mfma16(pa1, vl, acc[1][ot]);
        }

        asm volatile("s_waitcnt vmcnt(0)" ::: "memory");
        __syncthreads();
        cur ^= 1;
    }

    // ---- store partials: PA[bh][ks][n][o], PL[bh][ks][n] ----
    #pragma unroll
    for (int qb = 0; qb < 2; ++qb) {
        float* po = PA + (((size_t)(bh*KS + ks)*Nc + qrow0 + qb*16) << 6);
        #pragma unroll
        for (int ot = 0; ot < 4; ++ot)
            #pragma unroll
            for (int reg = 0; reg < 4; ++reg)
                po[(size_t)((4*l4 + reg) << 6) + ot*16 + l15] = acc[qb][ot][reg];
        #pragma unroll
        for (int r = 0; r < 4; ++r) {
            float v = lsum[qb][r];
            v += __shfl_xor(v, 1); v += __shfl_xor(v, 2);
            v += __shfl_xor(v, 4); v += __shfl_xor(v, 8);
            if (l15 == 0)
                PL[(size_t)(bh*KS + ks)*Nc + qrow0 + qb*16 + 4*l4 + r] = v;
        }
    }
}

// ---------------- merge: sum key-splits, divide, mean heads, leaky ----------------
__global__ void merge_kernel(const float* __restrict__ PA, const float* __restrict__ PL,
                             float* __restrict__ out, int KS)
{
    int gid = blockIdx.x*256 + threadIdx.x;   // B*N*64, o innermost
    int o  = gid & 63;
    int bn = gid >> 6;
    int n  = bn % Nc;
    int b  = bn / Nc;
    float ft = 0.f;
    for (int h = 0; h < Hc; ++h) {
        int bh = b*Hc + h;
        float A = 0.f, L = 0.f;
        for (int ks = 0; ks < KS; ++ks) {
            A += PA[(((size_t)(bh*KS + ks)*Nc + n) << 6) + o];
            L += PL[(size_t)(bh*KS + ks)*Nc + n];
        }
        ft += A / L;
    }
    ft *= 0.25f;
    out[((size_t)bn << 6) + o] = fmaxf(ft, 0.f) + 0.2f*fminf(ft, 0.f);
}

extern "C" void kernel_launch(void* const* d_in, const int* in_sizes, int n_in,
                              void* d_out, int out_size, void* d_ws, size_t ws_size,
                              hipStream_t stream)
{
    const float* x    = (const float*)d_in[0];
    const int*   edge = (const int*)d_in[1];
    const float* Wv   = (const float*)d_in[2];
    const float* bv   = (const float*)d_in[3];
    const float* Wq   = (const float*)d_in[4];
    const float* bq   = (const float*)d_in[5];
    const float* Wk   = (const float*)d_in[6];
    const float* bk   = (const float*)d_in[7];
    float* out = (float*)d_out;

    const size_t PROJ = (size_t)Bc*Hc*Nc*64;
    char* p = (char*)d_ws;
    float* Wt = (float*)p;              p += (size_t)3*Hc*64*64*sizeof(float);
    __bf16* Qh  = (__bf16*)p;           p += PROJ*2;
    __bf16* Ql  = (__bf16*)p;           p += PROJ*2;
    __bf16* Kh  = (__bf16*)p;           p += PROJ*2;
    __bf16* Kl  = (__bf16*)p;           p += PROJ*2;
    __bf16* Vh0 = (__bf16*)p;           p += PROJ*2;
    __bf16* Vl0 = (__bf16*)p;           p += PROJ*2;
    __bf16* Vth = (__bf16*)p;           p += PROJ*2;
    __bf16* Vtl = (__bf16*)p;           p += PROJ*2;
    uint32_t* pmT = (uint32_t*)p;       p += (size_t)Bc*NW32*Nc*4;

    int KS = 4;   // keys split 4 ways -> 768 blocks (3/CU resident)
    for (;;) {
        size_t need = (size_t)(p - (char*)d_ws)
                    + (size_t)Bc*Hc*KS*Nc*64*4 + (size_t)Bc*Hc*KS*Nc*4;
        if (need <= ws_size || KS == 1) break;
        KS >>= 1;
    }
    float* PA = (float*)p;              p += (size_t)Bc*Hc*KS*Nc*64*4;
    float* PL = (float*)p;

    hipLaunchKernelGGL(wt_kernel,   dim3(192),  dim3(256), 0, stream, Wq, Wk, Wv, Wt);
    hipLaunchKernelGGL(qkv_kernel,  dim3(1152), dim3(256), 0, stream,
                       x, Wt, bq, bk, bv, Qh, Ql, Kh, Kl, Vh0, Vl0);
    hipLaunchKernelGGL(vt_kernel,   dim3(Bc*Hc*48), dim3(256), 0, stream, Vh0, Vl0, Vth, Vtl);
    hipLaunchKernelGGL(pack_kernel, dim3(Bc*NW32*48/4), dim3(256), 0, stream, edge, pmT);
    hipLaunchKernelGGL(attn_mfma,   dim3(Bc*Hc*KS*24), dim3(256), 0, stream,
                       Qh, Ql, Kh, Kl, Vth, Vtl, pmT, PA, PL, KS, NW32/KS);
    hipLaunchKernelGGL(merge_kernel, dim3((Bc*Nc*64)/256), dim3(256), 0, stream,
                       PA, PL, out, KS);
}

// Round 4
// 107.228 us; speedup vs baseline: 7.9691x; 1.4921x over previous
//
#include <hip/hip_runtime.h>
#include <hip/hip_bf16.h>
#include <cstdint>

#define Bc 2
#define Nc 3072
#define Hc 4
#define NW32 96      // 32-key tiles per row

typedef __bf16 bf16x8 __attribute__((ext_vector_type(8)));
typedef float  f32x4  __attribute__((ext_vector_type(4)));
typedef float  f32x16 __attribute__((ext_vector_type(16)));

static __device__ __forceinline__ f32x16 mfma32(bf16x8 a, bf16x8 b, f32x16 c) {
    return __builtin_amdgcn_mfma_f32_32x32x16_bf16(a, b, c, 0, 0, 0);
}
static __device__ __forceinline__ void gload_lds16(const void* g, void* l) {
    __builtin_amdgcn_global_load_lds((const __attribute__((address_space(1))) void*)g,
                                     (__attribute__((address_space(3))) void*)l, 16, 0, 0);
}

// ---- W prep: [h][d][o] f32 -> Wb[p][h][o][d] bf16 hi/lo; Q pre-scaled by 0.125 ----
__global__ void wb_kernel(const float* __restrict__ Wq, const float* __restrict__ Wk,
                          const float* __restrict__ Wv,
                          const float* __restrict__ bq, const float* __restrict__ bk,
                          const float* __restrict__ bv,
                          __bf16* __restrict__ Wbh, __bf16* __restrict__ Wbl,
                          float* __restrict__ Bs)
{
    int i = blockIdx.x*256 + threadIdx.x;   // 49152
    int d = i & 63, o = (i >> 6) & 63, h = (i >> 12) & 3, p = i >> 14;
    const float* W = (p == 0) ? Wq : (p == 1) ? Wk : Wv;
    float scale = (p == 0) ? 0.125f : 1.0f;
    float val = W[(h*64 + d)*64 + o] * scale;
    int idx = (((p*Hc + h)*64 + o) << 6) + d;
    __bf16 hi = (__bf16)val;
    Wbh[idx] = hi;
    Wbl[idx] = (__bf16)(val - (float)hi);
    if (i < 3*Hc*64) {   // bias, pre-scaled: Bs[p][h][o]
        int pp = i / (Hc*64), rest = i % (Hc*64);
        const float* B = (pp == 0) ? bq : (pp == 1) ? bk : bv;
        Bs[i] = B[rest] * ((pp == 0) ? 0.125f : 1.0f);
    }
}

// ---- QKV projection via MFMA: planes [bh][n][64] bf16 hi/lo ----
__global__ __launch_bounds__(256) void qkv_mfma(
    const float* __restrict__ x, const __bf16* __restrict__ Wbh,
    const __bf16* __restrict__ Wbl, const float* __restrict__ Bs,
    __bf16* __restrict__ Qh, __bf16* __restrict__ Ql,
    __bf16* __restrict__ Kh, __bf16* __restrict__ Kl,
    __bf16* __restrict__ Vh0, __bf16* __restrict__ Vl0)
{
    const int lane = threadIdx.x & 63, w = threadIdx.x >> 6;
    const int l31 = lane & 31, hi = lane >> 5;
    int t = blockIdx.x;                 // 1152 blocks
    int nt = t % 48; t /= 48;
    int b  = t & 1;  t >>= 1;
    int p  = t % 3;
    int h  = t / 3;
    const int r0 = (w >> 1)*32, c0 = (w & 1)*32, n0 = nt*64;

    // A = x rows (hi/lo split), B = W cols
    bf16x8 xh[4], xl[4], wh[4], wl[4];
    #pragma unroll
    for (int kk = 0; kk < 4; ++kk) {
        size_t xoff = (((size_t)(b*Nc + n0 + r0 + l31)) << 6) + kk*16 + hi*8;
        float4 f0 = *(const float4*)(x + xoff);
        float4 f1 = *(const float4*)(x + xoff + 4);
        float xs[8] = {f0.x, f0.y, f0.z, f0.w, f1.x, f1.y, f1.z, f1.w};
        #pragma unroll
        for (int j = 0; j < 8; ++j) {
            __bf16 hh = (__bf16)xs[j];
            xh[kk][j] = hh;
            xl[kk][j] = (__bf16)(xs[j] - (float)hh);
        }
        size_t woff = (((size_t)((p*Hc + h)*64 + c0 + l31)) << 6) + kk*16 + hi*8;
        wh[kk] = *(const bf16x8*)(Wbh + woff);
        wl[kk] = *(const bf16x8*)(Wbl + woff);
    }
    float bias = Bs[(p*Hc + h)*64 + c0 + l31];
    f32x16 acc;
    #pragma unroll
    for (int i = 0; i < 16; ++i) acc[i] = bias;
    #pragma unroll
    for (int kk = 0; kk < 4; ++kk) {
        acc = mfma32(xh[kk], wh[kk], acc);
        acc = mfma32(xl[kk], wh[kk], acc);
        acc = mfma32(xh[kk], wl[kk], acc);
    }
    __bf16* dh = (p == 0) ? Qh : (p == 1) ? Kh : Vh0;
    __bf16* dl = (p == 0) ? Ql : (p == 1) ? Kl : Vl0;
    const int bh = b*Hc + h;
    #pragma unroll
    for (int r = 0; r < 16; ++r) {
        int row = (r & 3) + 8*(r >> 2) + 4*hi;
        size_t idx = (((size_t)bh*Nc + n0 + r0 + row) << 6) + c0 + l31;
        float val = acc[r];
        __bf16 hh = (__bf16)val;
        dh[idx] = hh;
        dl[idx] = (__bf16)(val - (float)hh);
    }
}

// ---- build per-tile 16KB LDS images: KVimg[bh][t] = {Kh|Kl|Vh|Vl} granules ----
// Kh/Kl granule (dc,key): K[key][dc*8..+7];  Vh/Vl granule (kb,o): V[kb*8..+7][o]
__global__ __launch_bounds__(256) void img_kernel(
    const __bf16* __restrict__ Kh, const __bf16* __restrict__ Kl,
    const __bf16* __restrict__ Vh0, const __bf16* __restrict__ Vl0,
    __bf16* __restrict__ KVimg)
{
    __shared__ __bf16 tile[32][64];
    const int tid = threadIdx.x;
    const int t = blockIdx.x % 96, bh = blockIdx.x / 96;
    char* img = (char*)KVimg + (((size_t)bh*96 + t) << 14);
    {
        int key = tid & 31, dc = tid >> 5;
        size_t src = (((size_t)bh*Nc + t*32 + key) << 6) + dc*8;
        *(bf16x8*)(img + (dc*32 + key)*16)        = *(const bf16x8*)(Kh + src);
        *(bf16x8*)(img + 4096 + (dc*32 + key)*16) = *(const bf16x8*)(Kl + src);
    }
    #pragma unroll
    for (int pl = 0; pl < 2; ++pl) {
        const __bf16* vp = pl ? Vl0 : Vh0;
        __syncthreads();
        {
            int n2 = tid >> 3, seg = (tid & 7)*8;
            *(bf16x8*)&tile[n2][seg] =
                *(const bf16x8*)(vp + (((size_t)bh*Nc + t*32 + n2) << 6) + seg);
        }
        __syncthreads();
        int o = tid & 63, kb = tid >> 6;
        __bf16 g[8];
        #pragma unroll
        for (int j = 0; j < 8; ++j) g[j] = tile[kb*8 + j][o];
        *(bf16x8*)(img + 8192 + pl*4096 + (kb*64 + o)*16) = *(bf16x8*)g;
    }
}

// ---- pack adjacency transposed: pmT[b][w][n], bit j = edge[b][n][32w+j] ----
__global__ void pack_kernel(const int* __restrict__ edge, uint32_t* __restrict__ pmT)
{
    int gw = blockIdx.x*4 + (threadIdx.x >> 6);
    int lane = threadIdx.x & 63;
    int ng = gw % 48; gw /= 48;
    int w  = gw % NW32; gw /= NW32;
    int b  = gw;
    int n = ng*64 + lane;
    const uint4* ep = (const uint4*)(edge + ((size_t)b*Nc + n)*Nc + w*32);
    uint32_t word = 0;
    #pragma unroll
    for (int i = 0; i < 8; ++i) {
        uint4 e = ep[i];
        word |= (e.x ? 1u : 0u) << (4*i);
        word |= (e.y ? 1u : 0u) << (4*i + 1);
        word |= (e.z ? 1u : 0u) << (4*i + 2);
        word |= (e.w ? 1u : 0u) << (4*i + 3);
    }
    pmT[((size_t)b*NW32 + w)*Nc + n] = word;
}

// ---- flash attention: 32x32 swapped QK^T, in-register softmax, LDS K/V images ----
__global__ __launch_bounds__(256, 3) void attn_mfma(
    const __bf16* __restrict__ Qh, const __bf16* __restrict__ Ql,
    const __bf16* __restrict__ KVimg, const uint32_t* __restrict__ pmT,
    float* __restrict__ PA, float* __restrict__ PL, int KS, int tps)
{
    __shared__ __align__(16) char ldsKV[2][16384];
    const int lane = threadIdx.x & 63, w = threadIdx.x >> 6;
    const int l31 = lane & 31, hi = lane >> 5;
    int gb = blockIdx.x;
    const int qt = gb % 24; gb /= 24;
    const int ks = gb % KS; gb /= KS;
    const int bh = gb, b = bh >> 2;
    const int qrow0 = qt*128 + w*32;

    // Q B-fragments (col = q-row = l31, k = d)
    bf16x8 qh[4], ql[4];
    #pragma unroll
    for (int kk = 0; kk < 4; ++kk) {
        size_t qoff = (((size_t)bh*Nc + qrow0 + l31) << 6) + kk*16 + hi*8;
        qh[kk] = *(const bf16x8*)(Qh + qoff);
        ql[kk] = *(const bf16x8*)(Ql + qoff);
    }

    f32x16 acc0, acc1;
    #pragma unroll
    for (int i = 0; i < 16; ++i) { acc0[i] = 0.f; acc1[i] = 0.f; }
    float lsum = 0.f;

    const char* img = (const char*)KVimg + (((size_t)bh*96) << 14);
    const int t0 = ks*tps;

    // prologue stage (wave w covers bytes [w*4096, w*4096+4096))
    #pragma unroll
    for (int g = 0; g < 4; ++g)
        gload_lds16(img + (((size_t)t0) << 14) + w*4096 + g*1024 + lane*16,
                    &ldsKV[0][w*4096 + g*1024]);
    asm volatile("s_waitcnt vmcnt(0)" ::: "memory");
    __syncthreads();

    int cur = 0;
    #pragma unroll 1
    for (int it = 0; it < tps; ++it) {
        const int t = t0 + it;
        if (it + 1 < tps) {
            #pragma unroll
            for (int g = 0; g < 4; ++g)
                gload_lds16(img + (((size_t)(t + 1)) << 14) + w*4096 + g*1024 + lane*16,
                            &ldsKV[cur ^ 1][w*4096 + g*1024]);
        }
        const char* Lb = &ldsKV[cur][0];

        // ---- QK^T (A = K from LDS, B = Q regs), 2 independent chains ----
        f32x16 scA, scB;
        #pragma unroll
        for (int i = 0; i < 16; ++i) { scA[i] = 0.f; scB[i] = 0.f; }
        #pragma unroll
        for (int kk = 0; kk < 4; ++kk) {
            bf16x8 ka = *(const bf16x8*)(Lb + ((kk*2 + hi) << 9) + (l31 << 4));
            bf16x8 la = *(const bf16x8*)(Lb + 4096 + ((kk*2 + hi) << 9) + (l31 << 4));
            if (kk < 2) {
                scA = mfma32(ka, qh[kk], scA);
                scA = mfma32(la, qh[kk], scA);
                scA = mfma32(ka, ql[kk], scA);
            } else {
                scB = mfma32(ka, qh[kk], scB);
                scB = mfma32(la, qh[kk], scB);
                scB = mfma32(ka, ql[kk], scB);
            }
        }
        f32x16 sc = scA + scB;   // scores: lane owns q=l31; reg r -> key (r&3)+8(r>>2)+4hi

        // ---- in-register softmax -> packed bf16 pairs ----
        uint32_t mw  = pmT[((size_t)b*NW32 + t)*Nc + qrow0 + l31];
        uint32_t mwh = mw >> (hi*4);
        uint32_t W8[8];
        #pragma unroll
        for (int i = 0; i < 8; ++i) {
            const int r0 = 2*i, r1 = 2*i + 1;
            const int bp0 = (r0 & 3) + 8*(r0 >> 2);
            const int bp1 = (r1 & 3) + 8*(r1 >> 2);
            float s0 = sc[2*i], s1 = sc[2*i + 1];
            float e0 = __expf(fmaxf(s0, 0.2f*s0));   // leaky(s) = max(s, 0.2s)
            float e1 = __expf(fmaxf(s1, 0.2f*s1));
            uint32_t m0 = (uint32_t)(((int)(mwh << (31 - bp0))) >> 31);
            uint32_t m1 = (uint32_t)(((int)(mwh << (31 - bp1))) >> 31);
            float p0 = __uint_as_float(__float_as_uint(e0) & m0);
            float p1 = __uint_as_float(__float_as_uint(e1) & m1);
            uint32_t wv;
            asm("v_cvt_pk_bf16_f32 %0, %1, %2" : "=v"(wv) : "v"(p0), "v"(p1));
            lsum += __uint_as_float(wv << 16);           // denom from SAME quantized vals
            lsum += __uint_as_float(wv & 0xffff0000u);
            W8[i] = wv;
        }
        // ---- permlane assembly of PV A-frags ----
        uint32_t a0 = W8[0], a2 = W8[2], a1 = W8[1], a3 = W8[3];
        uint32_t b0 = W8[4], b2 = W8[6], b1 = W8[5], b3 = W8[7];
        asm("v_permlane32_swap_b32 %0, %1" : "+v"(a0), "+v"(a2));
        asm("v_permlane32_swap_b32 %0, %1" : "+v"(a1), "+v"(a3));
        asm("v_permlane32_swap_b32 %0, %1" : "+v"(b0), "+v"(b2));
        asm("v_permlane32_swap_b32 %0, %1" : "+v"(b1), "+v"(b3));
        union { uint32_t u[4]; bf16x8 v; } pa0, pa1;
        pa0.u[0] = a0; pa0.u[1] = a1; pa0.u[2] = a2; pa0.u[3] = a3;
        pa1.u[0] = b0; pa1.u[1] = b1; pa1.u[2] = b2; pa1.u[3] = b3;

        // ---- PV (A = P regs, B = V from LDS) ----
        #pragma unroll
        for (int kkp = 0; kkp < 2; ++kkp) {
            bf16x8 pa = kkp ? pa1.v : pa0.v;
            #pragma unroll
            for (int ot = 0; ot < 2; ++ot) {
                bf16x8 vh = *(const bf16x8*)(Lb + 8192 + ((kkp*2 + hi) << 10)
                                             + ((ot*32 + l31) << 4));
                bf16x8 vl = *(const bf16x8*)(Lb + 12288 + ((kkp*2 + hi) << 10)
                                             + ((ot*32 + l31) << 4));
                if (ot == 0) { acc0 = mfma32(pa, vh, acc0); acc0 = mfma32(pa, vl, acc0); }
                else         { acc1 = mfma32(pa, vh, acc1); acc1 = mfma32(pa, vl, acc1); }
            }
        }

        asm volatile("s_waitcnt vmcnt(0)" ::: "memory");
        __syncthreads();
        cur ^= 1;
    }

    // ---- epilogue ----
    lsum += __shfl_xor(lsum, 32);
    float* po = PA + (((size_t)(bh*KS + ks)*Nc + qrow0) << 6);
    #pragma unroll
    for (int r = 0; r < 16; ++r) {
        int row = (r & 3) + 8*(r >> 2) + 4*hi;
        po[((size_t)row << 6) + l31]      = acc0[r];
        po[((size_t)row << 6) + 32 + l31] = acc1[r];
    }
    if (lane < 32)
        PL[(size_t)(bh*KS + ks)*Nc + qrow0 + l31] = lsum;
}

// ---- merge: sum key-splits, divide, mean heads, leaky ----
__global__ void merge_kernel(const float* __restrict__ PA, const float* __restrict__ PL,
                             float* __restrict__ out, int KS)
{
    int gid = blockIdx.x*256 + threadIdx.x;
    int o  = gid & 63;
    int bn = gid >> 6;
    int n  = bn % Nc;
    int b  = bn / Nc;
    float ft = 0.f;
    for (int h = 0; h < Hc; ++h) {
        int bh = b*Hc + h;
        float A = 0.f, L = 0.f;
        for (int ks = 0; ks < KS; ++ks) {
            A += PA[(((size_t)(bh*KS + ks)*Nc + n) << 6) + o];
            L += PL[(size_t)(bh*KS + ks)*Nc + n];
        }
        ft += A / L;
    }
    ft *= 0.25f;
    out[((size_t)bn << 6) + o] = fmaxf(ft, 0.f) + 0.2f*fminf(ft, 0.f);
}

extern "C" void kernel_launch(void* const* d_in, const int* in_sizes, int n_in,
                              void* d_out, int out_size, void* d_ws, size_t ws_size,
                              hipStream_t stream)
{
    const float* x    = (const float*)d_in[0];
    const int*   edge = (const int*)d_in[1];
    const float* Wv   = (const float*)d_in[2];
    const float* bv   = (const float*)d_in[3];
    const float* Wq   = (const float*)d_in[4];
    const float* bq   = (const float*)d_in[5];
    const float* Wk   = (const float*)d_in[6];
    const float* bk   = (const float*)d_in[7];
    float* out = (float*)d_out;

    const size_t PROJ = (size_t)Bc*Hc*Nc*64;          // 1.57M elems per plane
    char* p = (char*)d_ws;
    __bf16* Wbh = (__bf16*)p;   p += 49152*2;
    __bf16* Wbl = (__bf16*)p;   p += 49152*2;
    float*  Bs  = (float*)p;    p += 4096;
    __bf16* Qh  = (__bf16*)p;   p += PROJ*2;
    __bf16* Ql  = (__bf16*)p;   p += PROJ*2;
    __bf16* Kh  = (__bf16*)p;   p += PROJ*2;
    __bf16* Kl  = (__bf16*)p;   p += PROJ*2;
    __bf16* Vh0 = (__bf16*)p;   p += PROJ*2;
    __bf16* Vl0 = (__bf16*)p;   p += PROJ*2;
    __bf16* KVimg = (__bf16*)p; p += ((size_t)Bc*Hc*96) << 14;
    uint32_t* pmT = (uint32_t*)p; p += (size_t)Bc*NW32*Nc*4;

    int KS = 4;
    for (;;) {
        size_t need = (size_t)(p - (char*)d_ws)
                    + (size_t)Bc*Hc*KS*Nc*64*4 + (size_t)Bc*Hc*KS*Nc*4;
        if (need <= ws_size || KS == 1) break;
        KS >>= 1;
    }
    float* PA = (float*)p;      p += (size_t)Bc*Hc*KS*Nc*64*4;
    float* PL = (float*)p;

    hipLaunchKernelGGL(wb_kernel,  dim3(192),  dim3(256), 0, stream,
                       Wq, Wk, Wv, bq, bk, bv, Wbh, Wbl, Bs);
    hipLaunchKernelGGL(qkv_mfma,   dim3(1152), dim3(256), 0, stream,
                       x, Wbh, Wbl, Bs, Qh, Ql, Kh, Kl, Vh0, Vl0);
    hipLaunchKernelGGL(img_kernel, dim3(Bc*Hc*96), dim3(256), 0, stream,
                       Kh, Kl, Vh0, Vl0, KVimg);
    hipLaunchKernelGGL(pack_kernel, dim3(Bc*NW32*48/4), dim3(256), 0, stream, edge, pmT);
    hipLaunchKernelGGL(attn_mfma,  dim3(Bc*Hc*KS*24), dim3(256), 0, stream,
                       Qh, Ql, KVimg, pmT, PA, PL, KS, 96/KS);
    hipLaunchKernelGGL(merge_kernel, dim3((Bc*Nc*64)/256), dim3(256), 0, stream,
                       PA, PL, out, KS);
}